// Round 8
// baseline (59.724 us; speedup 1.0000x reference)
//
#include <hip/hip_runtime.h>
#include <hip/hip_cooperative_groups.h>

namespace cg = cooperative_groups;

// MMD loss: mean(delta @ delta.T) == ||colsum(source - target)||^2 / N^2.
// O(N*D) streaming reduction (67 MB read).
// R7 lessons: (a) contiguous-per-wave streams REGRESSED -> row-buffer theory
// refuted; R3/R6 strided shape is empirically best (~4.5-5 TB/s effective).
// (b) R5->R6 showed ~4 us per graph node (dropping a 4-byte memset saved
// 4.4 us). Biggest remaining lever: ONE dispatch.
// This version: single cooperative kernel (harness supports
// hipLaunchCooperativeKernel). Phase 1 = R3 load engine (256 blk x 1024 thr,
// 4 teams x 8 rows, 16 float4 loads in flight) + LDS fold + slice store.
// grid.sync(). Phase 2 = block b reduces float4-column b across 256 slices,
// squares, one atomicAdd per block. Fallback: proven 2-kernel R6 path.

#define MMD_N 8192
#define MMD_D 1024
#define CS_BLOCKS 256
#define CS_THREADS 1024
#define TEAMS 4
#define ROWS_PER_TEAM 8   // CS_BLOCKS * TEAMS * ROWS_PER_TEAM == MMD_N
#define INV_N2 1.4901161193847656e-8f  // 1 / 8192^2

__global__ __launch_bounds__(CS_THREADS) void mmd_fused(
    const float* __restrict__ src, const float* __restrict__ tgt,
    float* __restrict__ ws, float* __restrict__ out) {
    const int tid  = threadIdx.x;
    const int team = tid >> 8;    // 0..3
    const int col4 = tid & 255;   // float4 column
    const int row0 = blockIdx.x * (TEAMS * ROWS_PER_TEAM) + team * ROWS_PER_TEAM;
    const float4* s4 = reinterpret_cast<const float4*>(src);
    const float4* t4 = reinterpret_cast<const float4*>(tgt);

    if (blockIdx.x == 0 && tid == 0) out[0] = 0.f;

    // ---- phase 1: column partial sums (R3-proven shape) ----
    float4 acc = make_float4(0.f, 0.f, 0.f, 0.f);
#pragma unroll
    for (int r = 0; r < ROWS_PER_TEAM; ++r) {
        const int idx = (row0 + r) * (MMD_D / 4) + col4;
        float4 s = s4[idx];
        float4 t = t4[idx];
        acc.x += s.x - t.x;
        acc.y += s.y - t.y;
        acc.z += s.z - t.z;
        acc.w += s.w - t.w;
    }

    __shared__ float4 red[TEAMS][256];
    red[team][col4] = acc;
    __syncthreads();
    if (tid < 256) {
        float4 a = red[0][tid];
        float4 b = red[1][tid];
        float4 c = red[2][tid];
        float4 d = red[3][tid];
        float4 tot;
        tot.x = (a.x + b.x) + (c.x + d.x);
        tot.y = (a.y + b.y) + (c.y + d.y);
        tot.z = (a.z + b.z) + (c.z + d.z);
        tot.w = (a.w + b.w) + (c.w + d.w);
        reinterpret_cast<float4*>(ws)[blockIdx.x * 256 + tid] = tot;
    }

    // ---- grid-wide sync (device-scope fence included) ----
    cg::this_grid().sync();

    // ---- phase 2: block b folds float4-column b across 256 slices ----
    const float4* w4 = reinterpret_cast<const float4*>(ws);
    float4 colacc = make_float4(0.f, 0.f, 0.f, 0.f);
    if (tid < 256) {
        colacc = w4[tid * 256 + blockIdx.x];  // slice tid, column b
    }
    // reduce float4 over threads 0..255 (4 waves)
    const int lane = tid & 63;
    for (int off = 32; off > 0; off >>= 1) {
        colacc.x += __shfl_down(colacc.x, off, 64);
        colacc.y += __shfl_down(colacc.y, off, 64);
        colacc.z += __shfl_down(colacc.z, off, 64);
        colacc.w += __shfl_down(colacc.w, off, 64);
    }
    __shared__ float4 part[4];
    if (tid < 256 && lane == 0) part[tid >> 6] = colacc;
    __syncthreads();
    if (tid == 0) {
        float4 a = part[0], b = part[1], c = part[2], d = part[3];
        float4 tot;
        tot.x = (a.x + b.x) + (c.x + d.x);
        tot.y = (a.y + b.y) + (c.y + d.y);
        tot.z = (a.z + b.z) + (c.z + d.z);
        tot.w = (a.w + b.w) + (c.w + d.w);
        float sq = tot.x * tot.x + tot.y * tot.y + tot.z * tot.z + tot.w * tot.w;
        atomicAdd(out, sq * INV_N2);
    }
}

// ---------------- fallback: proven R6 2-kernel path ----------------
#define FB_BLOCKS 512
#define FB_THREADS 512
#define FB_TEAMS 2
#define FB_ROWS_PER_TEAM 8

__global__ __launch_bounds__(FB_THREADS) void mmd_colsum_fb(
    const float* __restrict__ src, const float* __restrict__ tgt,
    float* __restrict__ ws, float* __restrict__ out) {
    const int tid  = threadIdx.x;
    const int team = tid >> 8;
    const int col4 = tid & 255;
    const int row0 = blockIdx.x * (FB_TEAMS * FB_ROWS_PER_TEAM) + team * FB_ROWS_PER_TEAM;
    const float4* s4 = reinterpret_cast<const float4*>(src);
    const float4* t4 = reinterpret_cast<const float4*>(tgt);

    if (blockIdx.x == 0 && tid == 0) out[0] = 0.f;

    float4 s[FB_ROWS_PER_TEAM], t[FB_ROWS_PER_TEAM];
#pragma unroll
    for (int r = 0; r < FB_ROWS_PER_TEAM; ++r)
        s[r] = s4[(row0 + r) * (MMD_D / 4) + col4];
#pragma unroll
    for (int r = 0; r < FB_ROWS_PER_TEAM; ++r)
        t[r] = t4[(row0 + r) * (MMD_D / 4) + col4];

    float4 acc = make_float4(0.f, 0.f, 0.f, 0.f);
#pragma unroll
    for (int r = 0; r < FB_ROWS_PER_TEAM; ++r) {
        acc.x += s[r].x - t[r].x;
        acc.y += s[r].y - t[r].y;
        acc.z += s[r].z - t[r].z;
        acc.w += s[r].w - t[r].w;
    }

    __shared__ float4 red[FB_TEAMS][256];
    red[team][col4] = acc;
    __syncthreads();
    if (tid < 256) {
        float4 a = red[0][tid];
        float4 b = red[1][tid];
        float4 tot;
        tot.x = a.x + b.x; tot.y = a.y + b.y;
        tot.z = a.z + b.z; tot.w = a.w + b.w;
        reinterpret_cast<float4*>(ws)[blockIdx.x * 256 + tid] = tot;
    }
}

__global__ __launch_bounds__(256) void mmd_finale_fb(
    const float* __restrict__ ws, float* __restrict__ out) {
    const int tid  = threadIdx.x;
    const int j    = tid >> 6;
    const int lane = tid & 63;
    const int c    = blockIdx.x * 4 + j;
    const float4* w4 = reinterpret_cast<const float4*>(ws);

    float4 acc = make_float4(0.f, 0.f, 0.f, 0.f);
#pragma unroll
    for (int k = 0; k < FB_BLOCKS / 64; ++k) {
        float4 v = w4[(lane + 64 * k) * 256 + c];
        acc.x += v.x; acc.y += v.y; acc.z += v.z; acc.w += v.w;
    }
    for (int off = 32; off > 0; off >>= 1) {
        acc.x += __shfl_down(acc.x, off, 64);
        acc.y += __shfl_down(acc.y, off, 64);
        acc.z += __shfl_down(acc.z, off, 64);
        acc.w += __shfl_down(acc.w, off, 64);
    }
    if (lane == 0) {
        float sq = acc.x * acc.x + acc.y * acc.y + acc.z * acc.z + acc.w * acc.w;
        atomicAdd(out, sq * INV_N2);
    }
}

extern "C" void kernel_launch(void* const* d_in, const int* in_sizes, int n_in,
                              void* d_out, int out_size, void* d_ws, size_t ws_size,
                              hipStream_t stream) {
    const float* src = (const float*)d_in[0];
    const float* tgt = (const float*)d_in[1];
    float* out = (float*)d_out;
    float* ws = (float*)d_ws;  // needs CS_BLOCKS * MMD_D floats = 1 MiB

    void* args[] = {(void*)&src, (void*)&tgt, (void*)&ws, (void*)&out};
    hipError_t err = hipLaunchCooperativeKernel(
        (const void*)mmd_fused, dim3(CS_BLOCKS), dim3(CS_THREADS), args, 0, stream);
    if (err != hipSuccess) {
        // fallback: proven R6 2-kernel path
        mmd_colsum_fb<<<FB_BLOCKS, FB_THREADS, 0, stream>>>(src, tgt, ws, out);
        mmd_finale_fb<<<64, 256, 0, stream>>>(ws, out);
    }
}